// Round 1
// baseline (346.412 us; speedup 1.0000x reference)
//
#include <hip/hip_runtime.h>

#define N_NODES 50000
#define N_EDGES 800000
#define M_IDX   25000

// ---------------------------------------------------------------------------
// Edge kernel: 16 lanes per edge, lane o computes output channel o.
// Folded edge-MLP weights (lin_w*gamma, lin_b*gamma+beta) live in registers:
// per lane only the o-th column slice (3*CI + CI floats) is needed.
// ---------------------------------------------------------------------------
template<int CI>
__global__ __launch_bounds__(256) void edge_kernel(
    const float* __restrict__ pos,
    const int*   __restrict__ src,
    const int*   __restrict__ dst,
    const float* __restrict__ h,      // [N, CI]
    const float* __restrict__ lin_w,  // [3, CI*16]
    const float* __restrict__ lin_b,  // [CI*16]
    const float* __restrict__ gamma,  // [CI*16]
    const float* __restrict__ beta,   // [CI*16]
    float*       __restrict__ aggr,   // [N, 16]
    int E)
{
    const int o = threadIdx.x & 15;
    const int d = CI * 16;
    float W0[CI], W1[CI], W2[CI], B[CI];
#pragma unroll
    for (int i = 0; i < CI; ++i) {
        int j = i * 16 + o;
        float g = gamma[j];
        W0[i] = lin_w[j] * g;
        W1[i] = lin_w[d + j] * g;
        W2[i] = lin_w[2 * d + j] * g;
        B[i]  = fmaf(lin_b[j], g, beta[j]);
    }
    const int group   = (blockIdx.x * blockDim.x + threadIdx.x) >> 4;
    const int ngroups = (gridDim.x * blockDim.x) >> 4;
    for (int e = group; e < E; e += ngroups) {
        const int s = src[e];
        const int t = dst[e];
        const float p0 = pos[t * 3 + 0] - pos[s * 3 + 0];
        const float p1 = pos[t * 3 + 1] - pos[s * 3 + 1];
        const float p2 = pos[t * 3 + 2] - pos[s * 3 + 2];
        float x[CI];
        const float4* xp = (const float4*)(h + (size_t)s * CI);
#pragma unroll
        for (int q = 0; q < CI / 4; ++q) {
            float4 v = xp[q];
            x[4 * q + 0] = v.x; x[4 * q + 1] = v.y;
            x[4 * q + 2] = v.z; x[4 * q + 3] = v.w;
        }
        float msg = 0.f;
#pragma unroll
        for (int i = 0; i < CI; ++i) {
            float w = fmaf(p2, W2[i], fmaf(p1, W1[i], fmaf(p0, W0[i], B[i])));
            w = fmaxf(w, 0.f);
            msg = fmaf(x[i], w, msg);
        }
        atomicAdd(&aggr[(size_t)t * 16 + o], msg);
    }
}

// ---------------------------------------------------------------------------
// Degree count (same for all layers)
// ---------------------------------------------------------------------------
__global__ __launch_bounds__(256) void count_kernel(
    const int* __restrict__ dst, int* __restrict__ cnt, int E)
{
    int e = blockIdx.x * blockDim.x + threadIdx.x;
    if (e < E) atomicAdd(&cnt[dst[e]], 1);
}

// ---------------------------------------------------------------------------
// Node kernel: thread per (node, channel): relu(aggr/max(cnt,1) + h@root + bias)
// ---------------------------------------------------------------------------
template<int CI>
__global__ __launch_bounds__(256) void node_kernel(
    const float* __restrict__ aggr,   // [N,16]
    const int*   __restrict__ cnt,    // [N]
    const float* __restrict__ h_in,   // [N,CI]
    const float* __restrict__ root,   // [CI,16]
    const float* __restrict__ bias,   // [16]
    float*       __restrict__ h_out,  // [N,16]
    int N)
{
    int t = blockIdx.x * blockDim.x + threadIdx.x;
    if (t >= N * 16) return;
    int n = t >> 4, o = t & 15;
    float c = (float)cnt[n];
    float inv = 1.0f / fmaxf(c, 1.0f);
    float acc = fmaf(aggr[t], inv, bias[o]);
#pragma unroll
    for (int i = 0; i < CI; ++i)
        acc = fmaf(h_in[(size_t)n * CI + i], root[i * 16 + o], acc);
    h_out[t] = fmaxf(acc, 0.f);
}

// ---------------------------------------------------------------------------
// Output gather: out = [h[idx] (M*16) | pos[idx] (M*3) | batch[idx] (M)]
// ---------------------------------------------------------------------------
__global__ __launch_bounds__(256) void gather_kernel(
    const float* __restrict__ h,
    const float* __restrict__ pos,
    const int*   __restrict__ batch,
    const int*   __restrict__ idx,
    float*       __restrict__ out,
    int M)
{
    int j = blockIdx.x * blockDim.x + threadIdx.x;
    if (j >= M) return;
    int n = idx[j];
    float4*       o4 = (float4*)out + (size_t)j * 4;
    const float4* h4 = (const float4*)(h + (size_t)n * 16);
    o4[0] = h4[0]; o4[1] = h4[1]; o4[2] = h4[2]; o4[3] = h4[3];
    float* po = out + (size_t)M * 16 + (size_t)j * 3;
    po[0] = pos[n * 3 + 0];
    po[1] = pos[n * 3 + 1];
    po[2] = pos[n * 3 + 2];
    ((int*)out)[(size_t)M * 19 + j] = batch[n];
}

extern "C" void kernel_launch(void* const* d_in, const int* in_sizes, int n_in,
                              void* d_out, int out_size, void* d_ws, size_t ws_size,
                              hipStream_t stream) {
    const float* x      = (const float*)d_in[0];
    const float* pos    = (const float*)d_in[1];
    const float* lin_w0 = (const float*)d_in[2];
    const float* lin_b0 = (const float*)d_in[3];
    const float* gamma0 = (const float*)d_in[4];
    const float* beta0  = (const float*)d_in[5];
    const float* root0  = (const float*)d_in[6];
    const float* bias0  = (const float*)d_in[7];
    const float* lin_w1 = (const float*)d_in[8];
    const float* lin_b1 = (const float*)d_in[9];
    const float* gamma1 = (const float*)d_in[10];
    const float* beta1  = (const float*)d_in[11];
    const float* root1  = (const float*)d_in[12];
    const float* bias1  = (const float*)d_in[13];
    const float* lin_w2 = (const float*)d_in[14];
    const float* lin_b2 = (const float*)d_in[15];
    const float* gamma2 = (const float*)d_in[16];
    const float* beta2  = (const float*)d_in[17];
    const float* root2  = (const float*)d_in[18];
    const float* bias2  = (const float*)d_in[19];
    const int*   batch  = (const int*)d_in[20];
    const int*   idx    = (const int*)d_in[21];
    const int*   ei     = (const int*)d_in[22];
    const int*   src    = ei;
    const int*   dst    = ei + N_EDGES;
    float*       out    = (float*)d_out;

    // workspace layout (16B-aligned slices)
    float* aggr = (float*)d_ws;                 // N*16 floats
    float* hA   = aggr + (size_t)N_NODES * 16;  // N*16
    float* hB   = hA   + (size_t)N_NODES * 16;  // N*16
    int*   cnt  = (int*)(hB + (size_t)N_NODES * 16);  // N ints

    const int EB = 2048;   // edge-kernel blocks (grid-stride)
    const int NB = (N_NODES * 16 + 255) / 256;

    // degree counts (shared by all layers)
    hipMemsetAsync(cnt, 0, N_NODES * sizeof(int), stream);
    count_kernel<<<(N_EDGES + 255) / 256, 256, 0, stream>>>(dst, cnt, N_EDGES);

    // ---- layer 0: ci=8 -> co=16 ----
    hipMemsetAsync(aggr, 0, (size_t)N_NODES * 16 * sizeof(float), stream);
    edge_kernel<8><<<EB, 256, 0, stream>>>(pos, src, dst, x,
                                           lin_w0, lin_b0, gamma0, beta0,
                                           aggr, N_EDGES);
    node_kernel<8><<<NB, 256, 0, stream>>>(aggr, cnt, x, root0, bias0, hA, N_NODES);

    // ---- layer 1: ci=16 -> co=16 ----
    hipMemsetAsync(aggr, 0, (size_t)N_NODES * 16 * sizeof(float), stream);
    edge_kernel<16><<<EB, 256, 0, stream>>>(pos, src, dst, hA,
                                            lin_w1, lin_b1, gamma1, beta1,
                                            aggr, N_EDGES);
    node_kernel<16><<<NB, 256, 0, stream>>>(aggr, cnt, hA, root1, bias1, hB, N_NODES);

    // ---- layer 2: ci=16 -> co=16 ----
    hipMemsetAsync(aggr, 0, (size_t)N_NODES * 16 * sizeof(float), stream);
    edge_kernel<16><<<EB, 256, 0, stream>>>(pos, src, dst, hB,
                                            lin_w2, lin_b2, gamma2, beta2,
                                            aggr, N_EDGES);
    node_kernel<16><<<NB, 256, 0, stream>>>(aggr, cnt, hB, root2, bias2, hA, N_NODES);

    // ---- output gather ----
    gather_kernel<<<(M_IDX + 255) / 256, 256, 0, stream>>>(hA, pos, batch, idx, out, M_IDX);
}